// Round 12
// baseline (228.865 us; speedup 1.0000x reference)
//
#include <hip/hip_runtime.h>
#include <stdint.h>

// MultiHeadSelfAttention: E=1024, H=16, S=4096, half=512, Dh=32, scale=sqrt(64)=8
// Inputs fp32. THREE kernels total:
//   qkv:     Q/K/V = x_left @ W^T (x and W converted fp32->bf16 inline)
//   attn:    split-K flash attention (R8 structure + ones-column l-MFMA)
//   outproj: Y = combine(Op,l) @ Wo^T + bo (combine fused into A-staging,
//            Wo converted inline)

#define SEQ    4096
#define DMODEL 1024
#define DHALF  512
#define NH     16
#define DH     32

typedef __attribute__((ext_vector_type(4))) float facc4;
typedef __attribute__((ext_vector_type(8))) short bfrag8;

#define MFMA_BF16(a, b, c) __builtin_amdgcn_mfma_f32_16x16x32_bf16((a), (b), (c), 0, 0, 0)

static __device__ __forceinline__ uint16_t f2b(float x) {
    uint32_t u = __float_as_uint(x);
    return (uint16_t)((u + 0x7FFFu + ((u >> 16) & 1u)) >> 16);  // RNE
}
static __device__ __forceinline__ float b2f(uint16_t b) {
    return __uint_as_float(((uint32_t)b) << 16);
}

// 8x fp32 -> 8x bf16 (round-half-away; ties measure-small) via 2add+1perm pairs
static __device__ __forceinline__ bfrag8 cvt8perm(float4 a, float4 b) {
    uint32_t u0 = __float_as_uint(a.x) + 0x8000u, u1 = __float_as_uint(a.y) + 0x8000u;
    uint32_t u2 = __float_as_uint(a.z) + 0x8000u, u3 = __float_as_uint(a.w) + 0x8000u;
    uint32_t u4 = __float_as_uint(b.x) + 0x8000u, u5 = __float_as_uint(b.y) + 0x8000u;
    uint32_t u6 = __float_as_uint(b.z) + 0x8000u, u7 = __float_as_uint(b.w) + 0x8000u;
    union { uint32_t w[4]; bfrag8 r; } u;
    u.w[0] = __builtin_amdgcn_perm(u1, u0, 0x07060302u);
    u.w[1] = __builtin_amdgcn_perm(u3, u2, 0x07060302u);
    u.w[2] = __builtin_amdgcn_perm(u5, u4, 0x07060302u);
    u.w[3] = __builtin_amdgcn_perm(u7, u6, 0x07060302u);
    return u.r;
}

// ---------------------------------------------------------------------------
// 128x128-tile bf16 GEMM, double-buffered LDS.
// AMODE: 0 = A bf16, 1 = A fp32 (inline convert), 2 = A = combine(Op, lbuf)
//        (sum of ns unnormalized bf16 slabs / summed l; loads at staging time,
//         Op is L2-warm so exposure is small at K=512).
// BF32:  B fp32 (inline convert) vs bf16.
// ---------------------------------------------------------------------------
template <int AMODE, int BF32>
__device__ __forceinline__ void gemm128T(
    const void* __restrict__ A, int lda,
    const void* __restrict__ B, int ldb,
    void* __restrict__ C, int ldc, int cF32,
    const float* __restrict__ bias, float scale,
    int Kd, int m0, int n0,
    const float* __restrict__ lbuf, int ns)
{
    __shared__ __align__(16) uint16_t As[2][128 * 40];
    __shared__ __align__(16) uint16_t Bs[2][128 * 40];

    const int tid  = threadIdx.x;
    const int lane = tid & 63;
    const int wv   = tid >> 6;
    const int lo   = lane & 15;
    const int quad = lane >> 4;
    const int srow = tid >> 2;
    const int skq  = (tid & 3) * 8;
    const int rb   = (wv >> 1) * 64;
    const int cb   = (wv & 1) * 64;

    const facc4 ZACC = {0.f, 0.f, 0.f, 0.f};
    facc4 acc[4][4];
#pragma unroll
    for (int i = 0; i < 4; ++i)
#pragma unroll
        for (int j = 0; j < 4; ++j) acc[i][j] = ZACC;

    // prefetch registers (per mode; unused ones are dead-code eliminated)
    bfrag8 a_b[2]; float4 a_f[2][2];
    bfrag8 b_b[2]; float4 b_f[2][2];

    auto fetchA = [&](int kt) {
        if constexpr (AMODE == 0) {
#pragma unroll
            for (int hf = 0; hf < 2; ++hf)
                a_b[hf] = *(const bfrag8*)&((const uint16_t*)A)
                    [(size_t)(m0 + srow + hf * 64) * lda + kt + skq];
        } else if constexpr (AMODE == 1) {
#pragma unroll
            for (int hf = 0; hf < 2; ++hf) {
                const float* p = &((const float*)A)
                    [(size_t)(m0 + srow + hf * 64) * lda + kt + skq];
                a_f[hf][0] = *(const float4*)p;
                a_f[hf][1] = *(const float4*)(p + 4);
            }
        }
        // AMODE 2: no prefetch (loads at staging; L2-warm)
    };
    auto fetchB = [&](int kt) {
#pragma unroll
        for (int hf = 0; hf < 2; ++hf) {
            if constexpr (BF32) {
                const float* p = &((const float*)B)
                    [(size_t)(n0 + srow + hf * 64) * ldb + kt + skq];
                b_f[hf][0] = *(const float4*)p;
                b_f[hf][1] = *(const float4*)(p + 4);
            } else {
                b_b[hf] = *(const bfrag8*)&((const uint16_t*)B)
                    [(size_t)(n0 + srow + hf * 64) * ldb + kt + skq];
            }
        }
    };
    auto stage = [&](int kt, int buf) {
#pragma unroll
        for (int hf = 0; hf < 2; ++hf) {
            bfrag8 av;
            if constexpr (AMODE == 0) {
                av = a_b[hf];
            } else if constexpr (AMODE == 1) {
                av = cvt8perm(a_f[hf][0], a_f[hf][1]);
            } else {
                size_t row = (size_t)(m0 + srow + hf * 64);
                int h = kt >> 5;  // 8 cols within one head (skq < 32)
                float s[8] = {0.f,0.f,0.f,0.f,0.f,0.f,0.f,0.f};
                float l = 0.f;
                for (int sp = 0; sp < ns; ++sp) {
                    bfrag8 v = *(const bfrag8*)&((const uint16_t*)A)
                        [(size_t)sp * SEQ * DHALF + row * lda + kt + skq];
                    l += lbuf[((size_t)sp * NH + h) * SEQ + row];
#pragma unroll
                    for (int j = 0; j < 8; ++j) s[j] += b2f((uint16_t)v[j]);
                }
                float inv = 1.0f / l;
                float4 x0 = {s[0]*inv, s[1]*inv, s[2]*inv, s[3]*inv};
                float4 x1 = {s[4]*inv, s[5]*inv, s[6]*inv, s[7]*inv};
                av = cvt8perm(x0, x1);
            }
            *(bfrag8*)&As[buf][(srow + hf * 64) * 40 + skq] = av;

            bfrag8 bv;
            if constexpr (BF32) bv = cvt8perm(b_f[hf][0], b_f[hf][1]);
            else                bv = b_b[hf];
            *(bfrag8*)&Bs[buf][(srow + hf * 64) * 40 + skq] = bv;
        }
    };

    fetchA(0);
    fetchB(0);
    stage(0, 0);
    __syncthreads();

    int p = 0;
    for (int kt = 0; kt < Kd; kt += 32) {
        const bool more = (kt + 32 < Kd);
        if (more) { fetchA(kt + 32); fetchB(kt + 32); }  // fire-and-forget

        bfrag8 af[4], bf[4];
#pragma unroll
        for (int i = 0; i < 4; ++i) {
            af[i] = *(const bfrag8*)&As[p][(rb + i * 16 + lo) * 40 + quad * 8];
            bf[i] = *(const bfrag8*)&Bs[p][(cb + i * 16 + lo) * 40 + quad * 8];
        }
#pragma unroll
        for (int i = 0; i < 4; ++i)
#pragma unroll
            for (int j = 0; j < 4; ++j)
                acc[i][j] = MFMA_BF16(af[i], bf[j], acc[i][j]);

        if (more) {
            stage(kt + 32, 1 - p);
            __syncthreads();  // the only barrier per iter
            p ^= 1;
        }
    }

#pragma unroll
    for (int j = 0; j < 4; ++j) {
        int col  = n0 + cb + j * 16 + lo;
        float bv = bias ? bias[col] : 0.f;
#pragma unroll
        for (int i = 0; i < 4; ++i) {
#pragma unroll
            for (int r = 0; r < 4; ++r) {
                int row = m0 + rb + i * 16 + quad * 4 + r;
                float v = acc[i][j][r] * scale + bv;
                if (cF32) ((float*)C)[(size_t)row * ldc + col] = v;
                else      ((uint16_t*)C)[(size_t)row * ldc + col] = f2b(v);
            }
        }
    }
}

#define SC_Q (0.125f * 1.4426950408889634f)  // softmax scale * log2(e), folded into Q

// QKV from fp32 x (left half via lda=DMODEL) and fp32 weights, both inline-cvt.
__global__ __launch_bounds__(256, 2) void qkv_kernel(
    const float* __restrict__ x,
    const float* __restrict__ Wq, const float* __restrict__ Wk,
    const float* __restrict__ Wv,
    uint16_t* __restrict__ Q, uint16_t* __restrict__ K, uint16_t* __restrict__ V)
{
    const int z = blockIdx.z;
    const float* W = (z == 0) ? Wq : (z == 1) ? Wk : Wv;
    uint16_t* Out  = (z == 0) ? Q  : (z == 1) ? K  : V;
    float scale    = (z == 0) ? SC_Q : 1.0f;
    gemm128T<1, 1>(x, DMODEL, W, DHALF, Out, DHALF, 0, nullptr, scale, DHALF,
                   blockIdx.y * 128, blockIdx.x * 128, nullptr, 0);
}

// Out projection with fused combine: A = (sum_sp Op)/(sum_sp l), B = Wo fp32.
__global__ __launch_bounds__(256, 2) void outproj_kernel(
    const uint16_t* __restrict__ Op, const float* __restrict__ Wo,
    const float* __restrict__ bo, float* __restrict__ Y,
    const float* __restrict__ lbuf, int ns)
{
    gemm128T<2, 1>(Op, DHALF, Wo, DHALF, Y, DMODEL, 1, bo, 1.0f, DHALF,
                   blockIdx.y * 128, blockIdx.x * 128, lbuf, ns);
}

// ---------------------------------------------------------------------------
// Split-K flash attention (R8 structure + R11 ones-column l): unchanged from
// R11 (best measured: 91 us, occ 70%, VGPR 32).
// ---------------------------------------------------------------------------
__global__ __launch_bounds__(256) void attn_kernel(
    const uint16_t* __restrict__ Q, const uint16_t* __restrict__ Kb,
    const uint16_t* __restrict__ Vb, uint16_t* __restrict__ Op,
    float* __restrict__ lbuf, int kspan)
{
    __shared__ __align__(16) uint16_t Ks[64 * 40];     // K tile [key][d]
    __shared__ __align__(16) uint16_t Vt[32 * 64];     // V^T [d][key], swizzled
    __shared__ __align__(16) uint16_t Ps[4 * 16 * 72]; // per-wave P [q][key]

    const int tid  = threadIdx.x;
    const int lane = tid & 63;
    const int wv   = tid >> 6;
    const int lo   = lane & 15;
    const int quad = lane >> 4;
    const int h    = blockIdx.y;
    const int q0   = blockIdx.x * 64;
    const int sp   = blockIdx.z;
    const int srow = tid >> 2;
    const int skq  = (tid & 3) * 8;

    const facc4 ZACC = {0.f, 0.f, 0.f, 0.f};

    const bfrag8 qf = *(const bfrag8*)&Q[(size_t)(q0 + wv * 16 + lo) * DHALF + h * DH + quad * 8];

    bfrag8 ones;
#pragma unroll
    for (int j = 0; j < 8; ++j) ones[j] = (short)0x3F80;  // bf16 1.0

    int vt_w[8];
#pragma unroll
    for (int j = 0; j < 8; ++j) {
        int d  = skq + j;
        int Rd = ((d & 7) + 2 * (d >> 3)) & 7;
        vt_w[j] = d * 64 + ((((srow >> 3) + Rd) & 7) << 3) + (srow & 7);
    }
    int vt_r[2][2];
#pragma unroll
    for (int dt = 0; dt < 2; ++dt) {
        int d  = dt * 16 + lo;
        int Rd = ((d & 7) + 2 * (d >> 3)) & 7;
#pragma unroll
        for (int c = 0; c < 2; ++c)
            vt_r[c][dt] = d * 64 + ((((c * 4 + quad) + Rd) & 7) << 3);
    }
    const int pbase = wv * (16 * 72);
    const int ps_w  = pbase + lo * 72 + 4 * quad;
    const int ps_r  = pbase + lo * 72 + quad * 8;
    const int ks_r  = lo * 40 + quad * 8;

    const uint16_t* pK = &Kb[(size_t)srow * DHALF + h * DH + skq];
    const uint16_t* pV = &Vb[(size_t)srow * DHALF + h * DH + skq];

    facc4 oacc[2], oaccL;
    oacc[0] = ZACC; oacc[1] = ZACC; oaccL = ZACC;

    const int kb0  = sp * kspan;
    const int kend = kb0 + kspan;

    float4 kreg = *(const float4*)(pK + (size_t)kb0 * DHALF);
    float4 vreg = *(const float4*)(pV + (size_t)kb0 * DHALF);

    for (int kb = kb0; kb < kend; kb += 64) {
        *(float4*)&Ks[srow * 40 + skq] = kreg;
        {
            const uint16_t* vp = (const uint16_t*)&vreg;
#pragma unroll
            for (int j = 0; j < 8; ++j) Vt[vt_w[j]] = vp[j];
        }
        __syncthreads();

        if (kb + 64 < kend) {  // fire-and-forget prefetch of next K/V tile
            kreg = *(const float4*)(pK + (size_t)(kb + 64) * DHALF);
            vreg = *(const float4*)(pV + (size_t)(kb + 64) * DHALF);
        }

#pragma unroll
        for (int t = 0; t < 4; ++t) {
            bfrag8 kf = *(const bfrag8*)&Ks[t * 640 + ks_r];
            facc4 s = MFMA_BF16(kf, qf, ZACC);  // D[key=16t+4q+r][q=lo], pre-scaled
            float p0 = __builtin_amdgcn_exp2f(s[0]);
            float p1 = __builtin_amdgcn_exp2f(s[1]);
            float p2 = __builtin_amdgcn_exp2f(s[2]);
            float p3 = __builtin_amdgcn_exp2f(s[3]);
            uint32_t u0 = __float_as_uint(p0) + 0x8000u;
            uint32_t u1 = __float_as_uint(p1) + 0x8000u;
            uint32_t u2 = __float_as_uint(p2) + 0x8000u;
            uint32_t u3 = __float_as_uint(p3) + 0x8000u;
            uint2 w;
            w.x = __builtin_amdgcn_perm(u1, u0, 0x07060302u);
            w.y = __builtin_amdgcn_perm(u3, u2, 0x07060302u);
            *(uint2*)&Ps[ps_w + 16 * t] = w;  // single ds_write_b64
        }
        __builtin_amdgcn_wave_barrier();  // Ps is same-wave-only; pin DS order

#pragma unroll
        for (int c = 0; c < 2; ++c) {
            bfrag8 pf = *(const bfrag8*)&Ps[ps_r + c * 32];
#pragma unroll
            for (int dt = 0; dt < 2; ++dt) {
                bfrag8 vf = *(const bfrag8*)&Vt[vt_r[c][dt]];
                oacc[dt] = MFMA_BF16(pf, vf, oacc[dt]);
            }
            oaccL = MFMA_BF16(pf, ones, oaccL);  // l: D[q][*] = sum_k P[q][k]
        }
        __syncthreads();  // protect Ks/Vt restage
    }

    if (lo == 0) {
#pragma unroll
        for (int r = 0; r < 4; ++r)
            lbuf[((size_t)sp * NH + h) * SEQ + q0 + wv * 16 + quad * 4 + r] = oaccL[r];
    }

    uint16_t* Od = Op + (size_t)sp * SEQ * DHALF;
#pragma unroll
    for (int r = 0; r < 4; ++r) {
        int row = q0 + wv * 16 + quad * 4 + r;
        Od[(size_t)row * DHALF + h * DH + lo]      = f2b(oacc[0][r]);  // unnormalized
        Od[(size_t)row * DHALF + h * DH + 16 + lo] = f2b(oacc[1][r]);
    }
}

extern "C" void kernel_launch(void* const* d_in, const int* in_sizes, int n_in,
                              void* d_out, int out_size, void* d_ws, size_t ws_size,
                              hipStream_t stream)
{
    const float* x  = (const float*)d_in[0];
    const float* Wq = (const float*)d_in[1];
    const float* Wk = (const float*)d_in[2];
    const float* Wv = (const float*)d_in[3];
    const float* Wo = (const float*)d_in[4];
    const float* bo = (const float*)d_in[5];

    // ws (u16 elems): Q,K,V 2M ea | Op ns*2M | lbuf ns*NH*SEQ fp32
    size_t need4 = (3 + 4) * (size_t)SEQ * DHALF * 2 + 4 * (size_t)NH * SEQ * 4;
    const int ns = (ws_size >= need4) ? 4 : 2;

    uint16_t* Q  = (uint16_t*)d_ws;
    uint16_t* K  = Q + (size_t)SEQ * DHALF;
    uint16_t* V  = K + (size_t)SEQ * DHALF;
    uint16_t* Op = V + (size_t)SEQ * DHALF;
    float*  lbuf = (float*)(Op + (size_t)ns * SEQ * DHALF);

    qkv_kernel<<<dim3(DHALF / 128, SEQ / 128, 3), 256, 0, stream>>>(
        x, Wq, Wk, Wv, Q, K, V);
    attn_kernel<<<dim3(SEQ / 64, NH, ns), 256, 0, stream>>>(Q, K, V, Op, lbuf, SEQ / ns);
    outproj_kernel<<<dim3(DMODEL / 128, SEQ / 128), 256, 0, stream>>>(
        Op, Wo, bo, (float*)d_out, lbuf, ns);
}